// Round 3
// baseline (250.890 us; speedup 1.0000x reference)
//
#include <hip/hip_runtime.h>
#include <hip/hip_cooperative_groups.h>
#include <math.h>
#include <float.h>

namespace cg = cooperative_groups;

// Problem constants
#define B_ 64
#define M_ 16
#define A_ 128
#define H_ 128
#define P_ 16
#define NAT 100
#define NFP 2048
#define ZDIM (H_ + P_)     // 144
#define NROWS (NAT + NFP)  // 2148
#define NBM (B_ * M_)      // 1024
#define GRID 512           // 512 blocks x 256 thr = 2 blk/CU needed; __launch_bounds__(256,4) guarantees 4

// Scratch in static device globals — no reliance on ws_size.
__device__ float g_Ta[NAT * H_];       //  51 KB
__device__ float g_Tf[NFP * H_];       //   1 MB
__device__ float g_mol[NBM * H_];      // 512 KB

// One fused cooperative kernel, 3 phases separated by grid.sync().
// Block = 256 threads = two 128-thread "halves"; each half owns one row/bm.
__global__ __launch_bounds__(256, 4)
void fused_kernel(const int* __restrict__ af, const int* __restrict__ fpi,
                  const float* __restrict__ phys, const float* __restrict__ ratios,
                  const float* __restrict__ aemb, const float* __restrict__ femb,
                  const float* __restrict__ W_in, const float* __restrict__ b_in,
                  const float* __restrict__ ln_g, const float* __restrict__ ln_b,
                  const float* __restrict__ W1, const float* __restrict__ b1,
                  const float* __restrict__ W2, const float* __restrict__ b2,
                  float* __restrict__ out) {
    cg::grid_group grid = cg::this_grid();
    const int t = threadIdx.x;
    const int j = t & (H_ - 1);
    const int half = t >> 7;
    const int g = blockIdx.x;

    __shared__ float e_sh[2][H_];
    __shared__ int ia[2][A_];
    __shared__ int ifp[2][A_];

    // ---- Phase 1: T_a = atom_emb @ W_in[:128], T_f = fp_emb @ W_in[128:] ----
    // Row slots 2g+half, stride 2*gridDim. NAT=100 even => both halves of a
    // block always share the same trip count (barrier-safe).
    for (int r = g * 2 + half; r < NROWS; r += gridDim.x * 2) {
        const float* emb; const float* W; float* o;
        if (r < NAT) { emb = aemb + r * H_; W = W_in;            o = g_Ta + r * H_; }
        else { int rf = r - NAT; emb = femb + rf * H_; W = W_in + H_ * H_; o = g_Tf + rf * H_; }
        e_sh[half][j] = emb[j];
        __syncthreads();
        float acc = 0.f;
#pragma unroll 8
        for (int k = 0; k < H_; ++k) acc += e_sh[half][k] * W[k * H_ + j];
        o[j] = acc;
        __syncthreads();
    }

    grid.sync();

    // ---- Phase 2: mol[bm,j] = mean_a relu(T_a[af]+T_f[fp]+b_in) ----
    // 1024 bm over 1024 half-slots: exactly one iteration each.
    for (int bm = g * 2 + half; bm < NBM; bm += gridDim.x * 2) {
        ia[half][j]  = af[bm * A_ + j];
        ifp[half][j] = fpi[bm * A_ + j];
        __syncthreads();
        const float bj = b_in[j];
        float acc = 0.f;
#pragma unroll 8
        for (int a = 0; a < A_; ++a) {
            float v = g_Ta[ia[half][a] * H_ + j] + g_Tf[ifp[half][a] * H_ + j] + bj;
            acc += fmaxf(v, 0.f);
        }
        g_mol[bm * H_ + j] = acc * (1.0f / (float)A_);
        __syncthreads();
    }

    grid.sync();

    // ---- Phase 3: mix + LayerNorm + MLP head; block g handles batch b=g ----
    if (g < B_) {
        __shared__ float w[M_];
        __shared__ float z[ZDIM];
        __shared__ float zn[ZDIM];
        __shared__ float red[H_];
        const int b = g;

        if (t < M_) w[t] = ratios[b * M_ + t];
        __syncthreads();

        float rsum = 0.f;
#pragma unroll
        for (int m = 0; m < M_; ++m) rsum += w[m];
        const float dinv = 1.0f / (rsum + 1e-8f);

        if (t < H_) {                 // mix_h on threads 0..127
            float acc = 0.f;
#pragma unroll
            for (int m = 0; m < M_; ++m) acc += (w[m] * dinv) * g_mol[(b * M_ + m) * H_ + t];
            z[t] = acc;
        } else if (t < H_ + P_) {     // mix_p on threads 128..143, concurrent
            const int p = t - H_;
            float accp = 0.f;
#pragma unroll
            for (int m = 0; m < M_; ++m) {
                float pv = phys[(b * M_ + m) * P_ + p];
                if (isnan(pv)) pv = 0.f;
                else if (isinf(pv)) pv = (pv > 0.f) ? 1000.f : -1000.f;
                accp += (w[m] * dinv) * pv;
            }
            z[H_ + p] = accp;
        }
        __syncthreads();

        // LayerNorm stats (redundant per-thread; broadcast LDS reads)
        float s = 0.f;
#pragma unroll 8
        for (int k = 0; k < ZDIM; ++k) s += z[k];
        const float mu = s * (1.0f / (float)ZDIM);
        float s2 = 0.f;
#pragma unroll 8
        for (int k = 0; k < ZDIM; ++k) { float d = z[k] - mu; s2 += d * d; }
        const float rstd = rsqrtf(s2 * (1.0f / (float)ZDIM) + 1e-5f);

        if (t < ZDIM) zn[t] = (z[t] - mu) * rstd * ln_g[t] + ln_b[t];
        __syncthreads();

        if (t < H_) {                 // h1 col t, then fold W2
            float a1 = 0.f;
#pragma unroll 8
            for (int k = 0; k < ZDIM; ++k) a1 += zn[k] * W1[k * H_ + t];
            const float h1 = fmaxf(a1 + b1[t], 0.f);
            red[t] = h1 * W2[t];
        }
        __syncthreads();

        if (t == 0) {
            float y = b2[0];
#pragma unroll 8
            for (int k = 0; k < H_; ++k) y += red[k];
            // jnp.nan_to_num on output: nan->0, +/-inf->+/-FLT_MAX
            if (isnan(y)) y = 0.f;
            else if (isinf(y)) y = (y > 0.f) ? FLT_MAX : -FLT_MAX;
            out[b] = y;
        }
    }
}

extern "C" void kernel_launch(void* const* d_in, const int* in_sizes, int n_in,
                              void* d_out, int out_size, void* d_ws, size_t ws_size,
                              hipStream_t stream) {
    const int*   af    = (const int*)d_in[0];
    const int*   fpi   = (const int*)d_in[1];
    const float* phys  = (const float*)d_in[2];
    const float* ratio = (const float*)d_in[3];
    const float* aemb  = (const float*)d_in[4];
    const float* femb  = (const float*)d_in[5];
    const float* W_in  = (const float*)d_in[6];
    const float* b_in  = (const float*)d_in[7];
    const float* ln_g  = (const float*)d_in[8];
    const float* ln_b  = (const float*)d_in[9];
    const float* W1    = (const float*)d_in[10];
    const float* b1    = (const float*)d_in[11];
    const float* W2    = (const float*)d_in[12];
    const float* b2    = (const float*)d_in[13];
    float* out = (float*)d_out;

    void* args[] = {
        (void*)&af, (void*)&fpi, (void*)&phys, (void*)&ratio,
        (void*)&aemb, (void*)&femb, (void*)&W_in, (void*)&b_in,
        (void*)&ln_g, (void*)&ln_b, (void*)&W1, (void*)&b1,
        (void*)&W2, (void*)&b2, (void*)&out
    };
    hipLaunchCooperativeKernel((const void*)fused_kernel,
                               dim3(GRID), dim3(256), args, 0, stream);
}

// Round 4
// 109.293 us; speedup vs baseline: 2.2956x; 2.2956x over previous
//
#include <hip/hip_runtime.h>
#include <math.h>
#include <float.h>

// Problem constants
#define B_ 64
#define M_ 16
#define A_ 128
#define H_ 128
#define P_ 16
#define NAT 100
#define NFP 2048
#define ZDIM (H_ + P_)   // 144

// Scratch in static device globals — no reliance on ws_size.
__device__ float g_Ta[NAT * H_];       //  51 KB
__device__ float g_Tf[NFP * H_];       //   1 MB
__device__ float g_mol[B_ * M_ * H_];  // 512 KB

// K1: T_a[r,:] = atom_emb[r,:] @ W_in[0:128,:]   (r < 100)
//     T_f[r,:] = fp_emb[r,:]   @ W_in[128:256,:] (r < 2048)
// One block per table row, 128 threads (thread j = output col).
__global__ __launch_bounds__(128)
void k1_precompute(const float* __restrict__ atom_emb,
                   const float* __restrict__ fp_emb,
                   const float* __restrict__ W_in) {
    __shared__ float e[H_];
    const int r = blockIdx.x, j = threadIdx.x;
    const float* emb;
    const float* W;
    float* out;
    if (r < NAT) { emb = atom_emb + r * H_; W = W_in;             out = g_Ta + r * H_; }
    else { int rf = r - NAT; emb = fp_emb + rf * H_; W = W_in + H_ * H_; out = g_Tf + rf * H_; }
    e[j] = emb[j];
    __syncthreads();
    float acc = 0.f;
#pragma unroll 16
    for (int k = 0; k < H_; ++k) acc += e[k] * W[k * H_ + j];
    out[j] = acc;
}

// K2: mol[bm, j] = mean_a relu(T_a[af[bm,a], j] + T_f[fp[bm,a], j] + b_in[j])
// One block per (b,m), 128 threads. Gathers are L2-resident (T_a+T_f = 1.1 MB);
// deep unroll keeps many loads in flight against ~200-cycle L2 latency.
__global__ __launch_bounds__(128)
void k2_mol(const int* __restrict__ af, const int* __restrict__ fpi,
            const float* __restrict__ b_in) {
    __shared__ int ia[A_];
    __shared__ int ifp[A_];
    const int bm = blockIdx.x, j = threadIdx.x;
    ia[j]  = af[bm * A_ + j];
    ifp[j] = fpi[bm * A_ + j];
    __syncthreads();
    const float bj = b_in[j];
    float acc = 0.f;
#pragma unroll 16
    for (int a = 0; a < A_; ++a) {
        float v = g_Ta[ia[a] * H_ + j] + g_Tf[ifp[a] * H_ + j] + bj;
        acc += fmaxf(v, 0.f);
    }
    g_mol[bm * H_ + j] = acc * (1.0f / (float)A_);
}

// K3: per-batch mix + LayerNorm + MLP head. One block per b, 128 threads.
__global__ __launch_bounds__(128)
void k3_head(const float* __restrict__ phys,
             const float* __restrict__ ratios,
             const float* __restrict__ ln_g,
             const float* __restrict__ ln_b,
             const float* __restrict__ W1,
             const float* __restrict__ b1,
             const float* __restrict__ W2,
             const float* __restrict__ b2,
             float* __restrict__ out) {
    const int b = blockIdx.x, j = threadIdx.x;
    __shared__ float w[M_];
    __shared__ float z[ZDIM];
    __shared__ float zn[ZDIM];
    __shared__ float red[H_];

    if (j < M_) w[j] = ratios[b * M_ + j];
    __syncthreads();

    float rsum = 0.f;
#pragma unroll
    for (int m = 0; m < M_; ++m) rsum += w[m];
    const float dinv = 1.0f / (rsum + 1e-8f);

    // mix_h
    float acc = 0.f;
#pragma unroll
    for (int m = 0; m < M_; ++m) acc += (w[m] * dinv) * g_mol[(b * M_ + m) * H_ + j];
    z[j] = acc;

    // mix_p (threads 0..15)
    if (j < P_) {
        float accp = 0.f;
#pragma unroll
        for (int m = 0; m < M_; ++m) {
            float pv = phys[(b * M_ + m) * P_ + j];
            if (isnan(pv)) pv = 0.f;
            else if (isinf(pv)) pv = (pv > 0.f) ? 1000.f : -1000.f;
            accp += (w[m] * dinv) * pv;
        }
        z[H_ + j] = accp;
    }
    __syncthreads();

    // LayerNorm stats (redundant per-thread; broadcast LDS reads, cheap)
    float s = 0.f;
#pragma unroll 8
    for (int k = 0; k < ZDIM; ++k) s += z[k];
    const float mu = s * (1.0f / (float)ZDIM);
    float s2 = 0.f;
#pragma unroll 8
    for (int k = 0; k < ZDIM; ++k) { float d = z[k] - mu; s2 += d * d; }
    const float rstd = rsqrtf(s2 * (1.0f / (float)ZDIM) + 1e-5f);

    for (int k = j; k < ZDIM; k += H_)
        zn[k] = (z[k] - mu) * rstd * ln_g[k] + ln_b[k];
    __syncthreads();

    // h1 = relu(zn @ W1 + b1); thread j = column j
    float a1 = 0.f;
#pragma unroll 8
    for (int k = 0; k < ZDIM; ++k) a1 += zn[k] * W1[k * H_ + j];
    const float h1 = fmaxf(a1 + b1[j], 0.f);
    red[j] = h1 * W2[j];
    __syncthreads();

    if (j == 0) {
        float y = b2[0];
#pragma unroll 8
        for (int k = 0; k < H_; ++k) y += red[k];
        // jnp.nan_to_num: nan->0, +inf->FLT_MAX, -inf->-FLT_MAX
        if (isnan(y)) y = 0.f;
        else if (isinf(y)) y = (y > 0.f) ? FLT_MAX : -FLT_MAX;
        out[b] = y;
    }
}

extern "C" void kernel_launch(void* const* d_in, const int* in_sizes, int n_in,
                              void* d_out, int out_size, void* d_ws, size_t ws_size,
                              hipStream_t stream) {
    const int*   af    = (const int*)d_in[0];
    const int*   fpi   = (const int*)d_in[1];
    const float* phys  = (const float*)d_in[2];
    const float* ratio = (const float*)d_in[3];
    const float* aemb  = (const float*)d_in[4];
    const float* femb  = (const float*)d_in[5];
    const float* W_in  = (const float*)d_in[6];
    const float* b_in  = (const float*)d_in[7];
    const float* ln_g  = (const float*)d_in[8];
    const float* ln_b  = (const float*)d_in[9];
    const float* W1    = (const float*)d_in[10];
    const float* b1    = (const float*)d_in[11];
    const float* W2    = (const float*)d_in[12];
    const float* b2    = (const float*)d_in[13];
    float* out = (float*)d_out;

    k1_precompute<<<dim3(NAT + NFP), dim3(H_), 0, stream>>>(aemb, femb, W_in);
    k2_mol<<<dim3(B_ * M_), dim3(H_), 0, stream>>>(af, fpi, b_in);
    k3_head<<<dim3(B_), dim3(H_), 0, stream>>>(phys, ratio, ln_g, ln_b, W1, b1, W2, b2, out);
}

// Round 5
// 108.045 us; speedup vs baseline: 2.3221x; 1.0116x over previous
//
#include <hip/hip_runtime.h>
#include <math.h>
#include <float.h>

// Problem constants
#define B_ 64
#define M_ 16
#define A_ 128
#define H_ 128
#define P_ 16
#define NAT 100
#define NFP 2048
#define ZDIM (H_ + P_)   // 144

// Scratch in static device globals — no reliance on ws_size.
__device__ float g_Ta[NAT * H_];       //  51 KB
__device__ float g_Tf[NFP * H_];       //   1 MB
__device__ float g_mol[B_ * M_ * H_];  // 512 KB

// K1: T_a = atom_emb @ W_in[:128,:],  T_f = fp_emb @ W_in[128:,:]
// 4 rows per block (amortizes W_in L2 reads 4x: 137 MB -> 34 MB), 128 threads,
// thread j = output col, 4 independent accumulators for ILP.
// Blocks 0..24 cover T_a's 100 rows exactly; blocks 25..536 cover T_f's 2048.
#define K1_BLOCKS (NAT / 4 + NFP / 4)   // 25 + 512 = 537
__global__ __launch_bounds__(128)
void k1_precompute(const float* __restrict__ atom_emb,
                   const float* __restrict__ fp_emb,
                   const float* __restrict__ W_in) {
    __shared__ float e[4][H_];
    const int j = threadIdx.x;
    const float* emb; const float* W; float* out; int base;
    if (blockIdx.x < NAT / 4) {
        base = blockIdx.x * 4;           emb = atom_emb; W = W_in;            out = g_Ta;
    } else {
        base = (blockIdx.x - NAT / 4) * 4; emb = fp_emb;  W = W_in + H_ * H_; out = g_Tf;
    }
#pragma unroll
    for (int r = 0; r < 4; ++r) e[r][j] = emb[(base + r) * H_ + j];
    __syncthreads();
    float a0 = 0.f, a1 = 0.f, a2 = 0.f, a3 = 0.f;
#pragma unroll 8
    for (int k = 0; k < H_; ++k) {
        const float wk = W[k * H_ + j];   // coalesced, L1/L2-resident
        a0 += e[0][k] * wk;               // LDS broadcast reads (conflict-free)
        a1 += e[1][k] * wk;
        a2 += e[2][k] * wk;
        a3 += e[3][k] * wk;
    }
    out[(base + 0) * H_ + j] = a0;
    out[(base + 1) * H_ + j] = a1;
    out[(base + 2) * H_ + j] = a2;
    out[(base + 3) * H_ + j] = a3;
}

// K2: mol[bm,j] = mean_a relu(T_a[af[bm,a],j] + T_f[fp[bm,a],j] + b_in[j])
// One block per (b,m), 128 threads. float4 gathers: thread (s=t>>5, q=t&31)
// owns cols 4q..4q+3 and row-slot s (atoms a = s, s+4, ...). Each wave
// instruction fetches two full 512 B table rows. Partial sums reduced via LDS.
__global__ __launch_bounds__(128)
void k2_mol(const int* __restrict__ af, const int* __restrict__ fpi,
            const float* __restrict__ b_in) {
    __shared__ int ia[A_];
    __shared__ int ifp[A_];
    __shared__ float sh[4][H_];
    const int bm = blockIdx.x, t = threadIdx.x;
    const int q = t & 31, s = t >> 5;
    ia[t]  = af[bm * A_ + t];
    ifp[t] = fpi[bm * A_ + t];
    __syncthreads();
    const float4 bj = *(const float4*)&b_in[4 * q];
    float4 acc = make_float4(0.f, 0.f, 0.f, 0.f);
#pragma unroll 8
    for (int a = s; a < A_; a += 4) {
        const int ra = ia[a], rf = ifp[a];
        const float4 va = *(const float4*)&g_Ta[ra * H_ + 4 * q];
        const float4 vf = *(const float4*)&g_Tf[rf * H_ + 4 * q];
        acc.x += fmaxf(va.x + vf.x + bj.x, 0.f);
        acc.y += fmaxf(va.y + vf.y + bj.y, 0.f);
        acc.z += fmaxf(va.z + vf.z + bj.z, 0.f);
        acc.w += fmaxf(va.w + vf.w + bj.w, 0.f);
    }
    *(float4*)&sh[s][4 * q] = acc;
    __syncthreads();
    const int j = t;
    g_mol[bm * H_ + j] =
        (sh[0][j] + sh[1][j] + sh[2][j] + sh[3][j]) * (1.0f / (float)A_);
}

// K3: per-batch mix + LayerNorm + MLP head. One block per b, 128 threads.
__global__ __launch_bounds__(128)
void k3_head(const float* __restrict__ phys,
             const float* __restrict__ ratios,
             const float* __restrict__ ln_g,
             const float* __restrict__ ln_b,
             const float* __restrict__ W1,
             const float* __restrict__ b1,
             const float* __restrict__ W2,
             const float* __restrict__ b2,
             float* __restrict__ out) {
    const int b = blockIdx.x, j = threadIdx.x;
    __shared__ float w[M_];
    __shared__ float z[ZDIM];
    __shared__ float zn[ZDIM];
    __shared__ float red[H_];

    if (j < M_) w[j] = ratios[b * M_ + j];
    __syncthreads();

    float rsum = 0.f;
#pragma unroll
    for (int m = 0; m < M_; ++m) rsum += w[m];
    const float dinv = 1.0f / (rsum + 1e-8f);

    // mix_h
    float acc = 0.f;
#pragma unroll
    for (int m = 0; m < M_; ++m) acc += (w[m] * dinv) * g_mol[(b * M_ + m) * H_ + j];
    z[j] = acc;

    // mix_p (threads 0..15)
    if (j < P_) {
        float accp = 0.f;
#pragma unroll
        for (int m = 0; m < M_; ++m) {
            float pv = phys[(b * M_ + m) * P_ + j];
            if (isnan(pv)) pv = 0.f;
            else if (isinf(pv)) pv = (pv > 0.f) ? 1000.f : -1000.f;
            accp += (w[m] * dinv) * pv;
        }
        z[H_ + j] = accp;
    }
    __syncthreads();

    // LayerNorm stats (redundant per-thread; broadcast LDS reads, cheap)
    float s = 0.f;
#pragma unroll 8
    for (int k = 0; k < ZDIM; ++k) s += z[k];
    const float mu = s * (1.0f / (float)ZDIM);
    float s2 = 0.f;
#pragma unroll 8
    for (int k = 0; k < ZDIM; ++k) { float d = z[k] - mu; s2 += d * d; }
    const float rstd = rsqrtf(s2 * (1.0f / (float)ZDIM) + 1e-5f);

    for (int k = j; k < ZDIM; k += H_)
        zn[k] = (z[k] - mu) * rstd * ln_g[k] + ln_b[k];
    __syncthreads();

    // h1 = relu(zn @ W1 + b1); thread j = column j
    float a1 = 0.f;
#pragma unroll 8
    for (int k = 0; k < ZDIM; ++k) a1 += zn[k] * W1[k * H_ + j];
    const float h1 = fmaxf(a1 + b1[j], 0.f);
    red[j] = h1 * W2[j];
    __syncthreads();

    if (j == 0) {
        float y = b2[0];
#pragma unroll 8
        for (int k = 0; k < H_; ++k) y += red[k];
        // jnp.nan_to_num: nan->0, +inf->FLT_MAX, -inf->-FLT_MAX
        if (isnan(y)) y = 0.f;
        else if (isinf(y)) y = (y > 0.f) ? FLT_MAX : -FLT_MAX;
        out[b] = y;
    }
}

extern "C" void kernel_launch(void* const* d_in, const int* in_sizes, int n_in,
                              void* d_out, int out_size, void* d_ws, size_t ws_size,
                              hipStream_t stream) {
    const int*   af    = (const int*)d_in[0];
    const int*   fpi   = (const int*)d_in[1];
    const float* phys  = (const float*)d_in[2];
    const float* ratio = (const float*)d_in[3];
    const float* aemb  = (const float*)d_in[4];
    const float* femb  = (const float*)d_in[5];
    const float* W_in  = (const float*)d_in[6];
    const float* b_in  = (const float*)d_in[7];
    const float* ln_g  = (const float*)d_in[8];
    const float* ln_b  = (const float*)d_in[9];
    const float* W1    = (const float*)d_in[10];
    const float* b1    = (const float*)d_in[11];
    const float* W2    = (const float*)d_in[12];
    const float* b2    = (const float*)d_in[13];
    float* out = (float*)d_out;

    k1_precompute<<<dim3(K1_BLOCKS), dim3(H_), 0, stream>>>(aemb, femb, W_in);
    k2_mol<<<dim3(B_ * M_), dim3(H_), 0, stream>>>(af, fpi, b_in);
    k3_head<<<dim3(B_), dim3(H_), 0, stream>>>(phys, ratio, ln_g, ln_b, W1, b1, W2, b2, out);
}